// Round 2
// baseline (400.475 us; speedup 1.0000x reference)
//
#include <hip/hip_runtime.h>

// PlainVoxels (VolSDF-style) fused renderer — v2.
// One 512-thread block per ray; 8 lanes (one per trilinear corner) per sample.
// Each thread issues exactly ONE 16B gather; z-adjacent corners sit in
// adjacent lanes of the same instruction so the TA coalesces them into one
// cacheline transaction regardless of ray direction.
//
// Outputs (flat, N = #rays):
//   [0,3N) rgb | [3N,4N) depth | [4N,7N) normals | [7N,8N) acc
//   [8N,200N) sdf_grads (N*S,3) | [200N,201N) near | [201N,202N) far

constexpr int   GRID_R   = 256;
constexpr float CELL     = 0.015f;
constexpr float ORIGIN   = -1.92f;   // -0.5 * 256 * 0.015
constexpr int   S        = 64;
constexpr float MIN_BETA = 0.015f;

__global__ __launch_bounds__(512, 8)
void render_rays(const float* __restrict__ grid,
                 const float* __restrict__ beta_p,
                 const float* __restrict__ rays_o,
                 const float* __restrict__ rays_d,
                 const float* __restrict__ rdn,
                 const float* __restrict__ near_p,
                 const float* __restrict__ far_p,
                 float* __restrict__ out,
                 int N)
{
    const int ray  = blockIdx.x;
    const int tid  = threadIdx.x;
    const int s    = tid >> 3;          // sample 0..63
    const int c    = tid & 7;           // corner id
    const int ca   = (c >> 2) & 1;      // x corner
    const int cb   = (c >> 1) & 1;      // y corner
    const int cc   = c & 1;             // z corner (adjacent lanes share lines)
    const int wv   = tid >> 6;          // wave 0..7
    const int lane = tid & 63;

    __shared__ float wsum[8];           // per-wave tau totals
    __shared__ float redws[8][8];       // per-wave reduction partials

    const float nearv = near_p[0];
    const float farv  = far_p[0];
    const float dt    = (farv - nearv) / (float)S;
    const float t_mid = nearv + ((float)s + 0.5f) * dt;

    // ray params are block-uniform -> scalar loads
    const float ox = rays_o[3 * ray + 0];
    const float oy = rays_o[3 * ray + 1];
    const float oz = rays_o[3 * ray + 2];
    const float dxr = rays_d[3 * ray + 0];
    const float dyr = rays_d[3 * ray + 1];
    const float dzr = rays_d[3 * ray + 2];

    const float ux = (ox + t_mid * dxr - ORIGIN) / CELL;
    const float uy = (oy + t_mid * dyr - ORIGIN) / CELL;
    const float uz = (oz + t_mid * dzr - ORIGIN) / CELL;

    const bool inb = (ux >= 0.f) && (ux <= (float)(GRID_R - 1)) &&
                     (uy >= 0.f) && (uy <= (float)(GRID_R - 1)) &&
                     (uz >= 0.f) && (uz <= (float)(GRID_R - 1));

    int ix = (int)floorf(ux); ix = ix < 0 ? 0 : (ix > GRID_R - 2 ? GRID_R - 2 : ix);
    int iy = (int)floorf(uy); iy = iy < 0 ? 0 : (iy > GRID_R - 2 ? GRID_R - 2 : iy);
    int iz = (int)floorf(uz); iz = iz < 0 ? 0 : (iz > GRID_R - 2 ? GRID_R - 2 : iz);
    const float fx = ux - (float)ix;
    const float fy = uy - (float)iy;
    const float fz = uz - (float)iz;

    // this lane's corner weight and gradient signs
    const float wx = ca ? fx : 1.f - fx;   const float sx = ca ? 1.f : -1.f;
    const float wy = cb ? fy : 1.f - fy;   const float sy = cb ? 1.f : -1.f;
    const float wz = cc ? fz : 1.f - fz;   const float sz = cc ? 1.f : -1.f;

    // single 16B gather: channels 0..3 of this corner cell
    const int cell = (((ix + ca) << 8) + (iy + cb) << 8) + (iz + cc);
    const float* p = grid + (size_t)cell * 5;
    const float v0 = p[0], v1 = p[1], v2 = p[2], v3 = p[3];

    // per-corner partials: trilinear weight * value, and grad partials
    const float w3 = wx * wy * wz;
    float r0 = w3 * v0;                 // sdf
    float r1 = w3 * v1;                 // r
    float r2 = w3 * v2;                 // g
    float r3 = w3 * v3;                 // b
    float g0 = sx * wy * wz * v0;       // d/dfx
    float g1 = wx * sy * wz * v0;       // d/dfy
    float g2 = wx * wy * sz * v0;       // d/dfz

    // butterfly over the 8-corner group (strides 1,2,4): all 8 lanes end
    // with the full sums (group-uniform values — exploited below)
#pragma unroll
    for (int off = 1; off < 8; off <<= 1) {
        r0 += __shfl_xor(r0, off, 64);
        r1 += __shfl_xor(r1, off, 64);
        r2 += __shfl_xor(r2, off, 64);
        r3 += __shfl_xor(r3, off, 64);
        g0 += __shfl_xor(g0, off, 64);
        g1 += __shfl_xor(g1, off, 64);
        g2 += __shfl_xor(g2, off, 64);
    }

    const float gx = g0 / CELL;
    const float gy = g1 / CELL;
    const float gz = g2 / CELL;

    // sdf_grads: lanes c<3 write one component each (contiguous 12B/sample)
    if (c < 3) {
        const float gval = (c == 0) ? gx : ((c == 1) ? gy : gz);
        __builtin_nontemporal_store(gval,
            out + (size_t)8 * N + ((size_t)ray * S + s) * 3 + c);
    }

    // normals
    const float nrm = sqrtf(gx * gx + gy * gy + gz * gz);
    const float dn  = fmaxf(nrm, 1e-12f);
    const float nx = gx / dn, ny = gy / dn, nz = gz / dn;

    // Laplace-CDF density
    const float sdf = r0;
    const float beta_eff = MIN_BETA + fabsf(beta_p[0]);
    const float sgn = (sdf > 0.f) ? 1.f : ((sdf < 0.f) ? -1.f : 0.f);
    float sigma = (1.f / beta_eff) * (0.5f + 0.5f * sgn * expm1f(-fabsf(sdf) / beta_eff));
    sigma = inb ? sigma : 0.f;
    const float tau = sigma * dt;

    // ---- exclusive scan of tau over 64 samples ----
    // values are uniform within each 8-lane group, so lane-shifts of 8/16/32
    // perform the sample-level inclusive scan within this wave (8 samples)
    float incl = tau;
#pragma unroll
    for (int off = 8; off < 64; off <<= 1) {
        const float t = __shfl_up(incl, off, 64);
        if (lane >= off) incl += t;
    }
    if (lane == 63) wsum[wv] = incl;    // wave total
    __syncthreads();
    float pre = 0.f;
#pragma unroll
    for (int k = 0; k < 7; ++k) pre += (wv > k) ? wsum[k] : 0.f;
    const float cum = pre + incl;       // inclusive over all preceding samples

    const float T     = expf(-(cum - tau));
    const float alpha = -expm1f(-tau);
    const float wgt   = T * alpha;

    // ---- weighted reductions: rgb(3), depth, normals(3), acc ----
    float red[8];
    red[0] = wgt * r1;
    red[1] = wgt * r2;
    red[2] = wgt * r3;
    red[3] = wgt * t_mid;
    red[4] = wgt * nx;
    red[5] = wgt * ny;
    red[6] = wgt * nz;
    red[7] = wgt;
    // group-uniform again -> strides 8/16/32 sum the wave's 8 samples
#pragma unroll
    for (int off = 8; off < 64; off <<= 1) {
#pragma unroll
        for (int k = 0; k < 8; ++k)
            red[k] += __shfl_xor(red[k], off, 64);
    }
    if (lane == 0) {
#pragma unroll
        for (int k = 0; k < 8; ++k) redws[wv][k] = red[k];
    }
    __syncthreads();

    if (tid < 10) {
        const float inv_rdn = 1.f / rdn[ray];
        if (tid < 8) {
            float v = 0.f;
#pragma unroll
            for (int k = 0; k < 8; ++k) v += redws[k][tid];
            if (tid < 3)       out[3 * ray + tid] = v;
            else if (tid == 3) out[(size_t)3 * N + ray] = v * inv_rdn;
            else if (tid < 7)  out[(size_t)4 * N + 3 * ray + (tid - 4)] = v;
            else               out[(size_t)7 * N + ray] = v;
        } else if (tid == 8) {
            out[(size_t)200 * N + ray] = nearv * inv_rdn;
        } else {
            out[(size_t)201 * N + ray] = farv * inv_rdn;
        }
    }
}

extern "C" void kernel_launch(void* const* d_in, const int* in_sizes, int n_in,
                              void* d_out, int out_size, void* d_ws, size_t ws_size,
                              hipStream_t stream) {
    const float* grid   = (const float*)d_in[0];
    const float* beta   = (const float*)d_in[1];
    const float* rays_o = (const float*)d_in[2];
    const float* rays_d = (const float*)d_in[3];
    const float* rdn    = (const float*)d_in[4];
    const float* nearp  = (const float*)d_in[5];
    const float* farp   = (const float*)d_in[6];
    float* out = (float*)d_out;

    const int N = in_sizes[2] / 3;   // rays_o is (N,3)
    render_rays<<<N, 512, 0, stream>>>(grid, beta, rays_o, rays_d, rdn,
                                       nearp, farp, out, N);
}